// Round 3
// baseline (1924.975 us; speedup 1.0000x reference)
//
#include <hip/hip_runtime.h>

// Strategy: two-level bucketed gather, no per-node CSR, no fine scatter.
//  - Bin edges by dst>>7 into K=ceil(N/128) buckets (LDS-hist + block
//    reservation; packed entry (src<<7)|m, m = dst&127). Write-locality-
//    friendly (the round-2 k_scatter wrote 128MB HBM for 8MB payload).
//  - Per layer: transform kernel (3 linears) then one fused agg kernel:
//    block = bucket, LDS accumulators for 128 nodes x 32ch (T and I) with
//    node-rotated bank swizzle, LDS float atomics, fused mean+residual+relu.
//
// ws layout (4B units):
//   A[N*32] B[N*32] C[N*32] | ghistT[1024] ghistI[1024] | bsT[1025] bsI[1025]
//   curT[1024] curI[1024] | binT[E] binI[Ei]

#define BLK 256
#define RN 128          // nodes per bucket
#define KMAX 1024

__global__ __launch_bounds__(BLK) void k_bhist(const int* __restrict__ ei,
                                               int E, int* __restrict__ ghist,
                                               int K, int nblocks) {
  __shared__ int lh[KMAX];
  int t = threadIdx.x;
  for (int i = t; i < K; i += BLK) lh[i] = 0;
  __syncthreads();
  int chunk = (E + nblocks - 1) / nblocks;
  int cs = blockIdx.x * chunk;
  int ce = min(E, cs + chunk);
  for (int e = cs + t; e < ce; e += BLK) {
    int d = ei[E + e];
    atomicAdd(&lh[d >> 7], 1);
  }
  __syncthreads();
  for (int b = t; b < K; b += BLK)
    if (lh[b]) atomicAdd(&ghist[b], lh[b]);
}

// single block: exclusive scan of ghist[K] -> bs[0..K], also copy to cur
__global__ __launch_bounds__(1024) void k_bscan(const int* __restrict__ ghist,
                                                int* __restrict__ bs,
                                                int* __restrict__ cur, int K) {
  __shared__ int s[1024];
  int t = threadIdx.x;
  int v = (t < K) ? ghist[t] : 0;
  s[t] = v;
  __syncthreads();
  for (int off = 1; off < 1024; off <<= 1) {
    int x = (t >= off) ? s[t - off] : 0;
    __syncthreads();
    s[t] += x;
    __syncthreads();
  }
  if (t < K) {
    int excl = s[t] - v;
    bs[t] = excl;
    cur[t] = excl;
    if (t == K - 1) bs[K] = s[t];
  }
}

__global__ __launch_bounds__(BLK) void k_bin(const int* __restrict__ ei, int E,
                                             int* __restrict__ cur,
                                             int* __restrict__ binned, int K,
                                             int nblocks) {
  __shared__ int lh[KMAX];
  int t = threadIdx.x;
  for (int i = t; i < K; i += BLK) lh[i] = 0;
  __syncthreads();
  int chunk = (E + nblocks - 1) / nblocks;
  int cs = blockIdx.x * chunk;
  int ce = min(E, cs + chunk);
  for (int e = cs + t; e < ce; e += BLK) {
    int d = ei[E + e];
    atomicAdd(&lh[d >> 7], 1);
  }
  __syncthreads();
  // reserve: lh[b] becomes this block's running cursor for bucket b
  for (int b = t; b < K; b += BLK) {
    int c = lh[b];
    lh[b] = c ? atomicAdd(&cur[b], c) : 0;
  }
  __syncthreads();
  for (int e = cs + t; e < ce; e += BLK) {
    int src = ei[e];
    int d = ei[E + e];
    int pos = atomicAdd(&lh[d >> 7], 1);
    binned[pos] = (src << 7) | (d & 127);
  }
}

// layer-1 transforms: x[N,6] -> A=ht, B=hi, C=res
__global__ __launch_bounds__(BLK) void k_l1(
    const float* __restrict__ x, const float* __restrict__ Wt,
    const float* __restrict__ bt, const float* __restrict__ Wi,
    const float* __restrict__ bi, const float* __restrict__ Wr,
    const float* __restrict__ br, float* __restrict__ A, float* __restrict__ B,
    float* __restrict__ C, int N) {
  __shared__ float sWt[192], sWi[192], sWr[192], sb[96], sx[48];
  int t = threadIdx.x;
  if (t < 192) { sWt[t] = Wt[t]; sWi[t] = Wi[t]; sWr[t] = Wr[t]; }
  if (t < 32) { sb[t] = bt[t]; sb[32 + t] = bi[t]; sb[64 + t] = br[t]; }
  int gid = blockIdx.x * BLK + t;
  int nodeBase = (blockIdx.x * BLK) >> 5;
  if (t < 48) {
    int idx = nodeBase * 6 + t;
    if (idx < N * 6) sx[t] = x[idx];
  }
  __syncthreads();
  if (gid >= N * 32) return;
  int j = gid & 31, ln = t >> 5;
  const float* xr = sx + ln * 6;
  float at = sb[j], ai = sb[32 + j], ar = sb[64 + j];
#pragma unroll
  for (int k = 0; k < 6; ++k) {
    float xv = xr[k];
    at += xv * sWt[k * 32 + j];
    ai += xv * sWi[k * 32 + j];
    ar += xv * sWr[k * 32 + j];
  }
  A[gid] = at;
  B[gid] = ai;
  C[gid] = ar;
}

// layer-2 transforms: h=C[N,32] -> A=ht, B=hi, C=res (in-place safe)
__global__ __launch_bounds__(BLK) void k_l2(
    const float* __restrict__ h, const float* __restrict__ Wt,
    const float* __restrict__ bt, const float* __restrict__ Wi,
    const float* __restrict__ bi, const float* __restrict__ Wr,
    const float* __restrict__ br, float* __restrict__ A, float* __restrict__ B,
    float* __restrict__ C, int N) {
  __shared__ float sWt[1024], sWi[1024], sWr[1024], sb[96], hs[BLK];
  int t = threadIdx.x;
  for (int i = t; i < 1024; i += BLK) {
    sWt[i] = Wt[i];
    sWi[i] = Wi[i];
    sWr[i] = Wr[i];
  }
  if (t < 32) { sb[t] = bt[t]; sb[32 + t] = bi[t]; sb[64 + t] = br[t]; }
  int gid = blockIdx.x * BLK + t;
  hs[t] = (gid < N * 32) ? h[gid] : 0.0f;
  __syncthreads();
  if (gid >= N * 32) return;
  int j = t & 31, ln = t >> 5;
  float at = sb[j], ai = sb[32 + j], ar = sb[64 + j];
#pragma unroll
  for (int k = 0; k < 32; ++k) {
    float hv = hs[ln * 32 + k];
    at += hv * sWt[k * 32 + j];
    ai += hv * sWi[k * 32 + j];
    ar += hv * sWr[k * 32 + j];
  }
  A[gid] = at;
  B[gid] = ai;
  C[gid] = ar;
}

// fused bucket aggregation: block b owns nodes [b*128, b*128+128)
// LDS swizzle: phys(m,c) = m*32 + ((c + m) & 31)  (spreads banks per instr)
__global__ __launch_bounds__(BLK) void k_agg2(
    const float* __restrict__ A, const float* __restrict__ B,
    float* __restrict__ C, const int* __restrict__ bsT,
    const int* __restrict__ binT, const int* __restrict__ bsI,
    const int* __restrict__ binI, int N) {
  __shared__ float accT[RN * 32];
  __shared__ float accI[RN * 32];
  __shared__ int cnt[RN];
  int t = threadIdx.x;
  int b = blockIdx.x;
  for (int i = t; i < RN * 32; i += BLK) { accT[i] = 0.f; accI[i] = 0.f; }
  for (int i = t; i < RN; i += BLK) cnt[i] = 0;
  __syncthreads();
  int sub = t & 7;        // float4 chunk within row
  int grp = t >> 3;       // 32 edge lanes
  int c0 = sub * 4;
  {
    int e0 = bsT[b], e1 = bsT[b + 1];
    for (int i = e0 + grp; i < e1; i += BLK / 8) {
      int p = binT[i];
      int src = p >> 7, m = p & 127;
      const float4 v = *(const float4*)(A + (size_t)src * 32 + c0);
      int mb = m * 32;
      atomicAdd(&accT[mb + ((c0 + 0 + m) & 31)], v.x);
      atomicAdd(&accT[mb + ((c0 + 1 + m) & 31)], v.y);
      atomicAdd(&accT[mb + ((c0 + 2 + m) & 31)], v.z);
      atomicAdd(&accT[mb + ((c0 + 3 + m) & 31)], v.w);
    }
  }
  {
    int e0 = bsI[b], e1 = bsI[b + 1];
    for (int i = e0 + grp; i < e1; i += BLK / 8) {
      int p = binI[i];
      int src = p >> 7, m = p & 127;
      const float4 v = *(const float4*)(B + (size_t)src * 32 + c0);
      int mb = m * 32;
      atomicAdd(&accI[mb + ((c0 + 0 + m) & 31)], v.x);
      atomicAdd(&accI[mb + ((c0 + 1 + m) & 31)], v.y);
      atomicAdd(&accI[mb + ((c0 + 2 + m) & 31)], v.z);
      atomicAdd(&accI[mb + ((c0 + 3 + m) & 31)], v.w);
      if (sub == 0) atomicAdd(&cnt[m], 1);
    }
  }
  __syncthreads();
  int n0 = b * RN;
  for (int id = t; id < RN * 8; id += BLK) {
    int m = id >> 3, cg = id & 7;
    int n = n0 + m;
    if (n >= N) continue;
    int mb = m * 32;
    float inv = 1.0f / fmaxf((float)cnt[m], 1.0f);
    float* cp = C + (size_t)n * 32 + cg * 4;
    float4 r = *(const float4*)cp;
    float4 o;
    int i0 = (cg * 4 + 0 + m) & 31, i1 = (cg * 4 + 1 + m) & 31;
    int i2 = (cg * 4 + 2 + m) & 31, i3 = (cg * 4 + 3 + m) & 31;
    o.x = fmaxf(accT[mb + i0] + accI[mb + i0] * inv + r.x, 0.f);
    o.y = fmaxf(accT[mb + i1] + accI[mb + i1] * inv + r.y, 0.f);
    o.z = fmaxf(accT[mb + i2] + accI[mb + i2] * inv + r.z, 0.f);
    o.w = fmaxf(accT[mb + i3] + accI[mb + i3] * inv + r.w, 0.f);
    *(float4*)cp = o;
  }
}

__global__ __launch_bounds__(BLK) void k_cls(const float* __restrict__ h,
                                             const float* __restrict__ Wc,
                                             const float* __restrict__ bc,
                                             float* __restrict__ out, int N) {
  __shared__ float sW[224], sb[7];
  int t = threadIdx.x;
  if (t < 224) sW[t] = Wc[t];
  if (t < 7) sb[t] = bc[t];
  __syncthreads();
  int gid = blockIdx.x * BLK + t;
  if (gid >= N * 7) return;
  int n = gid / 7, j = gid - n * 7;
  const float* hr = h + n * 32;
  float a = sb[j];
#pragma unroll
  for (int k = 0; k < 32; ++k) a += hr[k] * sW[k * 7 + j];
  out[gid] = a;
}

extern "C" void kernel_launch(void* const* d_in, const int* in_sizes, int n_in,
                              void* d_out, int out_size, void* d_ws,
                              size_t ws_size, hipStream_t stream) {
  const float* x   = (const float*)d_in[0];
  const int* ei_t  = (const int*)d_in[1];
  const int* ei_i  = (const int*)d_in[2];
  const float* W1t = (const float*)d_in[3];
  const float* b1t = (const float*)d_in[4];
  const float* W1i = (const float*)d_in[5];
  const float* b1i = (const float*)d_in[6];
  const float* W1r = (const float*)d_in[7];
  const float* b1r = (const float*)d_in[8];
  const float* W2t = (const float*)d_in[9];
  const float* b2t = (const float*)d_in[10];
  const float* W2i = (const float*)d_in[11];
  const float* b2i = (const float*)d_in[12];
  const float* W2r = (const float*)d_in[13];
  const float* b2r = (const float*)d_in[14];
  const float* Wc  = (const float*)d_in[15];
  const float* bc  = (const float*)d_in[16];
  float* out = (float*)d_out;

  const int N  = in_sizes[0] / 6;
  const int E  = in_sizes[1] / 2;
  const int Ei = in_sizes[2] / 2;
  const int K  = (N + RN - 1) / RN;   // buckets (<= KMAX for N <= 131072)

  float* A = (float*)d_ws;
  float* B = A + (size_t)N * 32;
  float* C = B + (size_t)N * 32;
  int* ghistT = (int*)(C + (size_t)N * 32);
  int* ghistI = ghistT + KMAX;
  int* bsT    = ghistI + KMAX;
  int* bsI    = bsT + (KMAX + 1);
  int* curT   = bsI + (KMAX + 1);
  int* curI   = curT + KMAX;
  int* binT   = curI + KMAX;
  int* binI   = binT + E;

  const int gN32 = (N * 32 + BLK - 1) / BLK;
  const int gN7  = (N * 7 + BLK - 1) / BLK;
  const int NB   = 256;  // blocks for hist/bin chunking

  // ---- bucket build ----
  hipMemsetAsync(ghistT, 0, (size_t)2 * KMAX * sizeof(int), stream);
  k_bhist<<<NB, BLK, 0, stream>>>(ei_t, E, ghistT, K, NB);
  k_bhist<<<NB, BLK, 0, stream>>>(ei_i, Ei, ghistI, K, NB);
  k_bscan<<<1, 1024, 0, stream>>>(ghistT, bsT, curT, K);
  k_bscan<<<1, 1024, 0, stream>>>(ghistI, bsI, curI, K);
  k_bin<<<NB, BLK, 0, stream>>>(ei_t, E, curT, binT, K, NB);
  k_bin<<<NB, BLK, 0, stream>>>(ei_i, Ei, curI, binI, K, NB);

  // ---- Layer 1 ----
  k_l1<<<gN32, BLK, 0, stream>>>(x, W1t, b1t, W1i, b1i, W1r, b1r, A, B, C, N);
  k_agg2<<<K, BLK, 0, stream>>>(A, B, C, bsT, binT, bsI, binI, N);  // C = h1

  // ---- Layer 2 ----
  k_l2<<<gN32, BLK, 0, stream>>>(C, W2t, b2t, W2i, b2i, W2r, b2r, A, B, C, N);
  k_agg2<<<K, BLK, 0, stream>>>(A, B, C, bsT, binT, bsI, binI, N);  // C = h2

  // ---- Classifier ----
  k_cls<<<gN7, BLK, 0, stream>>>(C, Wc, bc, out, N);
}

// Round 4
// 438.199 us; speedup vs baseline: 4.3929x; 4.3929x over previous
//
#include <hip/hip_runtime.h>

// Strategy (round 4):
//  - Aggregate-then-transform (linearity of segment_sum over linear maps):
//      L1: gather raw x (padded to 8 floats, 32B/edge) -> sumT6/sumI6 per node,
//          then combine1: h1 = relu(sumT@Wt + degT*bt + (sumI/mI)@Wi + gate*bi
//                                   + x@Wr + br)
//      L2: gather h1 (one 12.8MB table, both edge types) -> aggT32/aggI32,
//          then combine2+classifier fused (h2 stays in LDS).
//  - CSR built without random HBM writes: coarse bucket binning (dst>>7) then
//    per-bucket LDS counting sort -> node-ordered csr + start/deg arrays.
//    Random writes confined to ~10KB/block regions (L2-absorbed).
//
// ws layout: A[N*32] B[N*32] C[N*32] (xp aliases C[0:N*8]) | int arrays | bins/csr

#define BLK 256
#define RN 128
#define KMAX 1024

// ---------------- bucket build ----------------
__global__ __launch_bounds__(BLK) void k_bhist(const int* __restrict__ ei,
                                               int E, int* __restrict__ ghist,
                                               int K, int nblocks) {
  __shared__ int lh[KMAX];
  int t = threadIdx.x;
  for (int i = t; i < K; i += BLK) lh[i] = 0;
  __syncthreads();
  int chunk = (E + nblocks - 1) / nblocks;
  int cs = blockIdx.x * chunk;
  int ce = min(E, cs + chunk);
  for (int e = cs + t; e < ce; e += BLK) atomicAdd(&lh[ei[E + e] >> 7], 1);
  __syncthreads();
  for (int b = t; b < K; b += BLK)
    if (lh[b]) atomicAdd(&ghist[b], lh[b]);
}

__global__ __launch_bounds__(1024) void k_bscan(const int* __restrict__ ghist,
                                                int* __restrict__ bs,
                                                int* __restrict__ cur, int K) {
  __shared__ int s[1024];
  int t = threadIdx.x;
  int v = (t < K) ? ghist[t] : 0;
  s[t] = v;
  __syncthreads();
  for (int off = 1; off < 1024; off <<= 1) {
    int x = (t >= off) ? s[t - off] : 0;
    __syncthreads();
    s[t] += x;
    __syncthreads();
  }
  if (t < K) {
    int excl = s[t] - v;
    bs[t] = excl;
    cur[t] = excl;
    if (t == K - 1) bs[K] = s[t];
  }
}

__global__ __launch_bounds__(BLK) void k_bin(const int* __restrict__ ei, int E,
                                             int* __restrict__ cur,
                                             int* __restrict__ binned, int K,
                                             int nblocks) {
  __shared__ int lh[KMAX];
  int t = threadIdx.x;
  for (int i = t; i < K; i += BLK) lh[i] = 0;
  __syncthreads();
  int chunk = (E + nblocks - 1) / nblocks;
  int cs = blockIdx.x * chunk;
  int ce = min(E, cs + chunk);
  for (int e = cs + t; e < ce; e += BLK) atomicAdd(&lh[ei[E + e] >> 7], 1);
  __syncthreads();
  for (int b = t; b < K; b += BLK) {
    int c = lh[b];
    lh[b] = c ? atomicAdd(&cur[b], c) : 0;
  }
  __syncthreads();
  for (int e = cs + t; e < ce; e += BLK) {
    int src = ei[e];
    int d = ei[E + e];
    int pos = atomicAdd(&lh[d >> 7], 1);
    binned[pos] = (src << 7) | (d & 127);
  }
}

// per-bucket counting sort -> node-ordered CSR + start/deg
__global__ __launch_bounds__(BLK) void k_sortcsr(
    const int* __restrict__ binned, const int* __restrict__ bs,
    int* __restrict__ csr, int* __restrict__ start, int* __restrict__ deg,
    int N) {
  __shared__ int h[RN], s[RN], cur[RN];
  int t = threadIdx.x, b = blockIdx.x;
  if (t < RN) h[t] = 0;
  __syncthreads();
  int e0 = bs[b], e1 = bs[b + 1];
  for (int i = e0 + t; i < e1; i += BLK) atomicAdd(&h[binned[i] & 127], 1);
  __syncthreads();
  if (t < RN) s[t] = h[t];
  __syncthreads();
  for (int off = 1; off < RN; off <<= 1) {
    int v = 0;
    if (t < RN && t >= off) v = s[t - off];
    __syncthreads();
    if (t < RN) s[t] += v;
    __syncthreads();
  }
  if (t < RN) {
    int excl = s[t] - h[t];
    int n = b * RN + t;
    if (n < N) {
      start[n] = e0 + excl;
      deg[n] = h[t];
    }
    cur[t] = excl;
  }
  __syncthreads();
  for (int i = e0 + t; i < e1; i += BLK) {
    int p = binned[i];
    int pos = atomicAdd(&cur[p & 127], 1);
    csr[e0 + pos] = p >> 7;  // writes land in this bucket's ~10KB region
  }
}

// ---------------- feature prep & layer 1 ----------------
__global__ __launch_bounds__(BLK) void k_prep(const float* __restrict__ x,
                                              float* __restrict__ xp, int N) {
  int gid = blockIdx.x * BLK + threadIdx.x;
  if (gid >= N * 8) return;
  int n = gid >> 3, c = gid & 7;
  xp[gid] = (c < 6) ? x[n * 6 + c] : 0.0f;
}

// gather raw x: 2 threads/node, float4 each. Outputs 8-float rows.
__global__ __launch_bounds__(BLK) void k_gather1(
    const float* __restrict__ xp, const int* __restrict__ startT,
    const int* __restrict__ degT, const int* __restrict__ csrT,
    const int* __restrict__ startI, const int* __restrict__ degI,
    const int* __restrict__ csrI, float* __restrict__ gT,
    float* __restrict__ gI, int N) {
  int gid = blockIdx.x * BLK + threadIdx.x;
  int n = gid >> 1;
  if (n >= N) return;
  int sub = gid & 1;
  const float4* xp4 = (const float4*)xp;
  float4 aT = {0.f, 0.f, 0.f, 0.f};
  {
    int s0 = startT[n], d = degT[n];
    const int* c = csrT + s0;
    for (int k = 0; k < d; ++k) {
      float4 v = xp4[(size_t)c[k] * 2 + sub];
      aT.x += v.x; aT.y += v.y; aT.z += v.z; aT.w += v.w;
    }
  }
  float4 aI = {0.f, 0.f, 0.f, 0.f};
  {
    int s0 = startI[n], d = degI[n];
    const int* c = csrI + s0;
    for (int k = 0; k < d; ++k) {
      float4 v = xp4[(size_t)c[k] * 2 + sub];
      aI.x += v.x; aI.y += v.y; aI.z += v.z; aI.w += v.w;
    }
  }
  ((float4*)gT)[(size_t)n * 2 + sub] = aT;
  ((float4*)gI)[(size_t)n * 2 + sub] = aI;
}

// h1 = relu(gT6@Wt + degT*bt + (gI6/mI)@Wi + gate*bi + x@Wr + br)
__global__ __launch_bounds__(BLK) void k_combine1(
    const float* __restrict__ gT, const float* __restrict__ gI,
    const float* __restrict__ x, const int* __restrict__ degT,
    const int* __restrict__ degI, const float* __restrict__ Wt,
    const float* __restrict__ bt, const float* __restrict__ Wi,
    const float* __restrict__ bi, const float* __restrict__ Wr,
    const float* __restrict__ br, float* __restrict__ h1, int N) {
  __shared__ float sWt[192], sWi[192], sWr[192], sb[96];
  __shared__ float sGT[64], sGI[64], sx[48];
  __shared__ float sdT[8], sdI[8];
  int t = threadIdx.x;
  if (t < 192) { sWt[t] = Wt[t]; sWi[t] = Wi[t]; sWr[t] = Wr[t]; }
  if (t < 32) { sb[t] = bt[t]; sb[32 + t] = bi[t]; sb[64 + t] = br[t]; }
  int nodeBase = (blockIdx.x * BLK) >> 5;  // 8 nodes per block
  if (t < 64) {
    int idx = nodeBase * 8 + t;
    if (idx < N * 8) { sGT[t] = gT[idx]; sGI[t] = gI[idx]; }
  }
  if (t < 48) {
    int idx = nodeBase * 6 + t;
    if (idx < N * 6) sx[t] = x[idx];
  }
  if (t < 8) {
    int n = nodeBase + t;
    if (n < N) { sdT[t] = (float)degT[n]; sdI[t] = (float)degI[n]; }
  }
  __syncthreads();
  int gid = blockIdx.x * BLK + t;
  if (gid >= N * 32) return;
  int j = t & 31, ln = t >> 5;
  float dT = sdT[ln], dI = sdI[ln];
  float mI = fmaxf(dI, 1.0f);
  float invI = 1.0f / mI;
  float gate = (dI > 0.0f) ? 1.0f : 0.0f;
  float acc = dT * sb[j] + gate * sb[32 + j] + sb[64 + j];
#pragma unroll
  for (int k = 0; k < 6; ++k) {
    acc += sGT[ln * 8 + k] * sWt[k * 32 + j];
    acc += sGI[ln * 8 + k] * invI * sWi[k * 32 + j];
    acc += sx[ln * 6 + k] * sWr[k * 32 + j];
  }
  h1[gid] = fmaxf(acc, 0.0f);
}

// ---------------- layer 2 ----------------
// gather h1: 8 threads/node, both edge types from one table.
__global__ __launch_bounds__(BLK) void k_gather2(
    const float* __restrict__ h1, const int* __restrict__ startT,
    const int* __restrict__ degT, const int* __restrict__ csrT,
    const int* __restrict__ startI, const int* __restrict__ degI,
    const int* __restrict__ csrI, float* __restrict__ aggT,
    float* __restrict__ aggI, int N) {
  int gid = blockIdx.x * BLK + threadIdx.x;
  int n = gid >> 3;
  if (n >= N) return;
  int sub = gid & 7;
  float4 aT = {0.f, 0.f, 0.f, 0.f};
  {
    int s0 = startT[n], d = degT[n];
    const int* c = csrT + s0;
    for (int k = 0; k < d; ++k) {
      const float4 v = *(const float4*)(h1 + (size_t)c[k] * 32 + sub * 4);
      aT.x += v.x; aT.y += v.y; aT.z += v.z; aT.w += v.w;
    }
  }
  float4 aI = {0.f, 0.f, 0.f, 0.f};
  {
    int s0 = startI[n], d = degI[n];
    const int* c = csrI + s0;
    for (int k = 0; k < d; ++k) {
      const float4 v = *(const float4*)(h1 + (size_t)c[k] * 32 + sub * 4);
      aI.x += v.x; aI.y += v.y; aI.z += v.z; aI.w += v.w;
    }
  }
  *(float4*)(aggT + (size_t)n * 32 + sub * 4) = aT;
  *(float4*)(aggI + (size_t)n * 32 + sub * 4) = aI;
}

// h2 = relu(aggT@W2t + degT*b2t + (aggI/mI)@W2i + gate*b2i + h1@W2r + b2r)
// out = h2@Wc + bc   (h2 stays in LDS)
__global__ __launch_bounds__(BLK) void k_combine2cls(
    const float* __restrict__ aggT, const float* __restrict__ aggI,
    const float* __restrict__ h1, const int* __restrict__ degT,
    const int* __restrict__ degI, const float* __restrict__ Wt,
    const float* __restrict__ bt, const float* __restrict__ Wi,
    const float* __restrict__ bi, const float* __restrict__ Wr,
    const float* __restrict__ br, const float* __restrict__ Wc,
    const float* __restrict__ bc, float* __restrict__ out, int N) {
  __shared__ float sWt[1024], sWi[1024], sWr[1024], sWc[224];
  __shared__ float sb[96], sbc[7];
  __shared__ float hT[BLK], hI[BLK], hR[BLK], hs2[BLK];
  __shared__ float sdT[8], sdI[8];
  int t = threadIdx.x;
  for (int i = t; i < 1024; i += BLK) {
    sWt[i] = Wt[i];
    sWi[i] = Wi[i];
    sWr[i] = Wr[i];
  }
  if (t < 224) sWc[t] = Wc[t];
  if (t < 32) { sb[t] = bt[t]; sb[32 + t] = bi[t]; sb[64 + t] = br[t]; }
  if (t < 7) sbc[t] = bc[t];
  int gid = blockIdx.x * BLK + t;
  int nodeBase = (blockIdx.x * BLK) >> 5;
  if (gid < N * 32) {
    hT[t] = aggT[gid];
    hI[t] = aggI[gid];
    hR[t] = h1[gid];
  } else {
    hT[t] = 0.f; hI[t] = 0.f; hR[t] = 0.f;
  }
  if (t < 8) {
    int n = nodeBase + t;
    sdT[t] = (n < N) ? (float)degT[n] : 0.f;
    sdI[t] = (n < N) ? (float)degI[n] : 0.f;
  }
  __syncthreads();
  int j = t & 31, ln = t >> 5;
  float dT = sdT[ln], dI = sdI[ln];
  float mI = fmaxf(dI, 1.0f);
  float invI = 1.0f / mI;
  float gate = (dI > 0.0f) ? 1.0f : 0.0f;
  float acc = dT * sb[j] + gate * sb[32 + j] + sb[64 + j];
#pragma unroll
  for (int k = 0; k < 32; ++k) {
    acc += hT[ln * 32 + k] * sWt[k * 32 + j];
    acc += hI[ln * 32 + k] * invI * sWi[k * 32 + j];
    acc += hR[ln * 32 + k] * sWr[k * 32 + j];
  }
  hs2[t] = fmaxf(acc, 0.0f);
  __syncthreads();
  if (j < 7) {
    int n = nodeBase + ln;
    if (n < N) {
      float a = sbc[j];
#pragma unroll
      for (int k = 0; k < 32; ++k) a += hs2[ln * 32 + k] * sWc[k * 7 + j];
      out[(size_t)n * 7 + j] = a;
    }
  }
}

extern "C" void kernel_launch(void* const* d_in, const int* in_sizes, int n_in,
                              void* d_out, int out_size, void* d_ws,
                              size_t ws_size, hipStream_t stream) {
  const float* x   = (const float*)d_in[0];
  const int* ei_t  = (const int*)d_in[1];
  const int* ei_i  = (const int*)d_in[2];
  const float* W1t = (const float*)d_in[3];
  const float* b1t = (const float*)d_in[4];
  const float* W1i = (const float*)d_in[5];
  const float* b1i = (const float*)d_in[6];
  const float* W1r = (const float*)d_in[7];
  const float* b1r = (const float*)d_in[8];
  const float* W2t = (const float*)d_in[9];
  const float* b2t = (const float*)d_in[10];
  const float* W2i = (const float*)d_in[11];
  const float* b2i = (const float*)d_in[12];
  const float* W2r = (const float*)d_in[13];
  const float* b2r = (const float*)d_in[14];
  const float* Wc  = (const float*)d_in[15];
  const float* bc  = (const float*)d_in[16];
  float* out = (float*)d_out;

  const int N  = in_sizes[0] / 6;
  const int E  = in_sizes[1] / 2;
  const int Ei = in_sizes[2] / 2;
  const int K  = (N + RN - 1) / RN;

  float* A = (float*)d_ws;            // aggT32 (L2); gT (L1, first N*8)
  float* B = A + (size_t)N * 32;      // aggI32 (L2); gI (L1, first N*8)
  float* C = B + (size_t)N * 32;      // xp (first N*8), then h1
  int* ghistT = (int*)(C + (size_t)N * 32);
  int* ghistI = ghistT + KMAX;
  int* bsT    = ghistI + KMAX;
  int* bsI    = bsT + (KMAX + 1);
  int* curT   = bsI + (KMAX + 1);
  int* curI   = curT + KMAX;
  int* startT = curI + KMAX;
  int* degT   = startT + N;
  int* startI = degT + N;
  int* degI   = startI + N;
  int* binT   = degI + N;
  int* binI   = binT + E;
  int* csrT   = binI + Ei;
  int* csrI   = csrT + E;

  const int gN32 = (N * 32 + BLK - 1) / BLK;
  const int gN8  = (N * 8 + BLK - 1) / BLK;
  const int gN2  = (N * 2 + BLK - 1) / BLK;
  const int NB   = 256;

  // ---- CSR build (bucket bin + per-bucket counting sort) ----
  hipMemsetAsync(ghistT, 0, (size_t)2 * KMAX * sizeof(int), stream);
  k_bhist<<<NB, BLK, 0, stream>>>(ei_t, E, ghistT, K, NB);
  k_bhist<<<NB, BLK, 0, stream>>>(ei_i, Ei, ghistI, K, NB);
  k_bscan<<<1, 1024, 0, stream>>>(ghistT, bsT, curT, K);
  k_bscan<<<1, 1024, 0, stream>>>(ghistI, bsI, curI, K);
  k_bin<<<NB, BLK, 0, stream>>>(ei_t, E, curT, binT, K, NB);
  k_bin<<<NB, BLK, 0, stream>>>(ei_i, Ei, curI, binI, K, NB);
  k_sortcsr<<<K, BLK, 0, stream>>>(binT, bsT, csrT, startT, degT, N);
  k_sortcsr<<<K, BLK, 0, stream>>>(binI, bsI, csrI, startI, degI, N);

  // ---- Layer 1 (aggregate raw x, then transform) ----
  k_prep<<<gN8, BLK, 0, stream>>>(x, C, N);  // xp in C
  k_gather1<<<gN2, BLK, 0, stream>>>(C, startT, degT, csrT, startI, degI,
                                     csrI, A, B, N);
  k_combine1<<<gN32, BLK, 0, stream>>>(A, B, x, degT, degI, W1t, b1t, W1i,
                                       b1i, W1r, b1r, C, N);  // C = h1

  // ---- Layer 2 (aggregate h1, then transform + classifier fused) ----
  k_gather2<<<gN8, BLK, 0, stream>>>(C, startT, degT, csrT, startI, degI,
                                     csrI, A, B, N);
  k_combine2cls<<<gN32, BLK, 0, stream>>>(A, B, C, degT, degI, W2t, b2t, W2i,
                                          b2i, W2r, b2r, Wc, bc, out, N);
}